// Round 1
// baseline (209.226 us; speedup 1.0000x reference)
//
#include <hip/hip_runtime.h>
#include <cstddef>

// ---------------- constants ----------------
#define BATCH 4096
#define TT 26          // sparse tables
#define LL 4           // lookups per table
#define NROWS 100000
#define MM 64          // embedding dim
#define RSTRIDE 416    // padded R row stride (64 + 351 = 415 real + 1 pad)

// ---------------- bottom layer 0: (4096,13)->(4096,512) ----------------
__global__ __launch_bounds__(256) void bot0_kernel(
    const float* __restrict__ x, const float* __restrict__ W,
    const float* __restrict__ bias, float* __restrict__ out)
{
    int b = blockIdx.x;
    __shared__ float xr[13];
    if (threadIdx.x < 13) xr[threadIdx.x] = x[b * 13 + threadIdx.x];
    __syncthreads();
    for (int j = threadIdx.x; j < 512; j += 256) {
        const float* w = W + j * 13;
        float s = bias[j];
#pragma unroll
        for (int k = 0; k < 13; k++) s = fmaf(xr[k], w[k], s);
        out[(size_t)b * 512 + j] = fmaxf(s, 0.f);
    }
}

// ---------------- generic tiled GEMM: C = act(A @ W^T + bias) ----------------
// A: (4096, K) row-major stride lda ; W: (N, K) row-major stride ldw
// BM=BN=64, BK=16, 256 threads, 4x4 outputs/thread
#define BM 64
#define BN 64
#define BK 16

template<int ACT>  // 0 = none, 1 = relu
__global__ __launch_bounds__(256) void gemm_bias_act(
    const float* __restrict__ A, int lda,
    const float* __restrict__ W, int ldw,
    const float* __restrict__ bias,
    float* __restrict__ C, int ldc,
    int K, int Kreal)
{
    __shared__ float As[BK][BM + 4];
    __shared__ float Ws[BK][BN + 4];
    const int tid = threadIdx.x;
    const int bm = blockIdx.x * BM;
    const int bn = blockIdx.y * BN;
    const int tx = tid & 15;   // n-dir
    const int ty = tid >> 4;   // m-dir
    const int lr = tid >> 4;   // 0..15 (row group for loads)
    const int lk = tid & 15;   // 0..15 (k within tile)

    float acc[4][4] = {};

    for (int k0 = 0; k0 < K; k0 += BK) {
#pragma unroll
        for (int i = 0; i < 4; i++) {
            int m = lr + i * 16;
            As[lk][m] = A[(size_t)(bm + m) * lda + k0 + lk];
            int n = lr + i * 16;
            float w = (k0 + lk < Kreal) ? W[(size_t)(bn + n) * ldw + k0 + lk] : 0.f;
            Ws[lk][n] = w;
        }
        __syncthreads();
#pragma unroll
        for (int kk = 0; kk < BK; kk++) {
            float4 av = *(const float4*)&As[kk][ty * 4];
            float4 wv = *(const float4*)&Ws[kk][tx * 4];
            float a_[4] = {av.x, av.y, av.z, av.w};
            float w_[4] = {wv.x, wv.y, wv.z, wv.w};
#pragma unroll
            for (int i = 0; i < 4; i++)
#pragma unroll
                for (int j = 0; j < 4; j++)
                    acc[i][j] = fmaf(a_[i], w_[j], acc[i][j]);
        }
        __syncthreads();
    }

#pragma unroll
    for (int i = 0; i < 4; i++) {
        int m = bm + ty * 4 + i;
#pragma unroll
        for (int j = 0; j < 4; j++) {
            int n = bn + tx * 4 + j;
            float v = acc[i][j] + bias[n];
            if (ACT == 1) v = fmaxf(v, 0.f);
            C[(size_t)m * ldc + n] = v;
        }
    }
}

// ---------------- embedding gather + Tcat assembly ----------------
// Tcat: (4096, 27, 64); row 0 = x3, rows 1..26 = sum of 4 embedding rows
__global__ __launch_bounds__(256) void embed_tcat_kernel(
    const int* __restrict__ idx, const float* __restrict__ emb,
    const float* __restrict__ x3, float* __restrict__ Tcat, int nrows)
{
    int gid = blockIdx.x * 4 + (threadIdx.x >> 6);
    int lane = threadIdx.x & 63;
    if (gid >= nrows) return;
    int b = gid / 27;
    int r = gid - b * 27;
    float* dst = Tcat + (size_t)gid * MM;
    if (r == 0) {
        dst[lane] = x3[(size_t)b * MM + lane];
    } else {
        int t = r - 1;
        const int* ip = idx + ((size_t)b * TT + t) * LL;
        const float* tab = emb + (size_t)t * NROWS * MM;
        float s = 0.f;
#pragma unroll
        for (int l = 0; l < LL; l++)
            s += tab[(size_t)ip[l] * MM + lane];
        dst[lane] = s;
    }
}

// ---------------- interaction: per-batch gram lower triangle -> R ----------------
// R: (4096, 416): [0..63]=x3, [64..414]=Zflat, [415]=0 pad
__global__ __launch_bounds__(256) void interact_kernel(
    const float* __restrict__ Tcat, float* __restrict__ R)
{
    __shared__ float S[27 * 68];
    int b = blockIdx.x;
    const float* src = Tcat + (size_t)b * 27 * MM;
    int tid = threadIdx.x;
    for (int i = tid; i < 27 * MM; i += 256) {
        int r = i >> 6, c = i & 63;
        S[r * 68 + c] = src[i];
    }
    __syncthreads();
    float* Rb = R + (size_t)b * RSTRIDE;
    if (tid < 64) Rb[tid] = S[tid];          // row 0 of S = x3
    if (tid == 64) Rb[415] = 0.f;            // pad column
    for (int e = tid; e < 351; e += 256) {
        int i = (int)((1.0f + sqrtf(1.0f + 8.0f * (float)e)) * 0.5f);
        while (i * (i - 1) / 2 > e) i--;
        while ((i + 1) * i / 2 <= e) i++;
        int j = e - i * (i - 1) / 2;
        const float* si = &S[i * 68];
        const float* sj = &S[j * 68];
        float s = 0.f;
#pragma unroll
        for (int k = 0; k < 16; k++) {
            float4 a = *(const float4*)&si[k * 4];
            float4 c4 = *(const float4*)&sj[k * 4];
            s += a.x * c4.x + a.y * c4.y + a.z * c4.z + a.w * c4.w;
        }
        Rb[64 + e] = s;
    }
}

// ---------------- top layer 2: (4096,256)->(4096,1), sigmoid ----------------
__global__ __launch_bounds__(256) void top2_kernel(
    const float* __restrict__ h, const float* __restrict__ W,
    const float* __restrict__ bias, float* __restrict__ out)
{
    __shared__ float ws[256];
    int tid = threadIdx.x;
    ws[tid] = W[tid];
    __syncthreads();
    int b = blockIdx.x * 4 + (tid >> 6);
    int lane = tid & 63;
    const float* hb = h + (size_t)b * 256;
    float4 hv = *(const float4*)&hb[lane * 4];
    float4 wv = *(const float4*)&ws[lane * 4];
    float s = hv.x * wv.x + hv.y * wv.y + hv.z * wv.z + hv.w * wv.w;
#pragma unroll
    for (int off = 32; off >= 1; off >>= 1)
        s += __shfl_xor(s, off, 64);
    if (lane == 0) {
        float v = s + bias[0];
        out[b] = 1.0f / (1.0f + expf(-v));
    }
}

// ---------------- launch ----------------
extern "C" void kernel_launch(void* const* d_in, const int* in_sizes, int n_in,
                              void* d_out, int out_size, void* d_ws, size_t ws_size,
                              hipStream_t stream) {
    const float* dense  = (const float*)d_in[0];
    const int*   sidx   = (const int*)d_in[1];
    const float* emb    = (const float*)d_in[2];
    const float* bw0    = (const float*)d_in[3];
    const float* bb0    = (const float*)d_in[4];
    const float* bw1    = (const float*)d_in[5];
    const float* bb1    = (const float*)d_in[6];
    const float* bw2    = (const float*)d_in[7];
    const float* bb2    = (const float*)d_in[8];
    const float* tw0    = (const float*)d_in[9];
    const float* tb0    = (const float*)d_in[10];
    const float* tw1    = (const float*)d_in[11];
    const float* tb1    = (const float*)d_in[12];
    const float* tw2    = (const float*)d_in[13];
    const float* tb2    = (const float*)d_in[14];
    float* out = (float*)d_out;

    float* ws = (float*)d_ws;
    // region0: x1 (2,097,152 fl) then Tcat (7,077,888 fl)
    float* x1   = ws;
    float* Tcat = ws;
    // region1: x2 (1,048,576) then h1 (2,097,152)
    float* x2 = ws + 7077888;
    float* h1 = ws + 7077888;
    // region2: x3
    float* x3 = ws + 9175040;
    // region3: R (4096*416)
    float* R  = ws + 9437184;
    // region4: h2
    float* h2 = ws + 11141120;

    // 1. bottom layer 0: dense (4096,13) -> x1 (4096,512)
    bot0_kernel<<<BATCH, 256, 0, stream>>>(dense, bw0, bb0, x1);

    // 2. bottom layer 1: x1 -> x2 (4096,256), K=512
    gemm_bias_act<1><<<dim3(BATCH / BM, 256 / BN), 256, 0, stream>>>(
        x1, 512, bw1, 512, bb1, x2, 256, 512, 512);

    // 3. bottom layer 2: x2 -> x3 (4096,64), K=256
    gemm_bias_act<1><<<dim3(BATCH / BM, 64 / BN), 256, 0, stream>>>(
        x2, 256, bw2, 256, bb2, x3, 64, 256, 256);

    // 4. embedding gather + Tcat (4096,27,64)
    {
        int nrows = BATCH * 27;
        embed_tcat_kernel<<<nrows / 4, 256, 0, stream>>>(sidx, emb, x3, Tcat, nrows);
    }

    // 5. interaction -> R (4096,416 padded)
    interact_kernel<<<BATCH, 256, 0, stream>>>(Tcat, R);

    // 6. top layer 0: R -> h1 (4096,512), K=416 padded (415 real)
    gemm_bias_act<1><<<dim3(BATCH / BM, 512 / BN), 256, 0, stream>>>(
        R, RSTRIDE, tw0, 415, tb0, h1, 512, RSTRIDE, 415);

    // 7. top layer 1: h1 -> h2 (4096,256), K=512
    gemm_bias_act<1><<<dim3(BATCH / BM, 256 / BN), 256, 0, stream>>>(
        h1, 512, tw1, 512, tb1, h2, 256, 512, 512);

    // 8. top layer 2: h2 -> out (4096,1), sigmoid
    top2_kernel<<<BATCH / 4, 256, 0, stream>>>(h2, tw2, tb2, out);
}

// Round 2
// 72.761 us; speedup vs baseline: 2.8755x; 2.8755x over previous
//
#include <hip/hip_runtime.h>
#include <hip/hip_bf16.h>
#include <cstddef>
#include <cstdint>

// ---------------- constants ----------------
#define BATCH 4096
#define TT 26          // sparse tables
#define LL 4           // lookups per table
#define NROWS 100000
#define MM 64          // embedding dim
#define RSTRIDE 416    // padded R row stride (64 + 351 real + 1 pad)

typedef __attribute__((ext_vector_type(8))) short bf16x8;
typedef __attribute__((ext_vector_type(4))) float f32x4;

#define AS1 __attribute__((address_space(1)))
#define AS3 __attribute__((address_space(3)))

__device__ __forceinline__ void gload_lds16(const void* g, void* l) {
    __builtin_amdgcn_global_load_lds((const AS1 unsigned int*)g,
                                     (AS3 unsigned int*)l, 16, 0, 0);
}

__device__ __forceinline__ float bu2f(unsigned short u) {
    unsigned int x = (unsigned int)u << 16;
    float f; __builtin_memcpy(&f, &x, 4); return f;
}

// ---------------- weight conversion fp32 -> bf16 (per launch, ~2MB) ----------------
// bw1b (256,512), bw2b (64,256), tw0b (512,416 padded from 415), tw1b (256,512)
__global__ __launch_bounds__(256) void convert_weights(
    const float* __restrict__ bw1, const float* __restrict__ bw2,
    const float* __restrict__ tw0, const float* __restrict__ tw1,
    __hip_bfloat16* __restrict__ bw1b, __hip_bfloat16* __restrict__ bw2b,
    __hip_bfloat16* __restrict__ tw0b, __hip_bfloat16* __restrict__ tw1b)
{
    int i = blockIdx.x * 256 + threadIdx.x;
    if (i < 131072) {
        bw1b[i] = __float2bfloat16(bw1[i]);
    } else if (i < 147456) {
        int j = i - 131072; bw2b[j] = __float2bfloat16(bw2[j]);
    } else if (i < 360448) {
        int j = i - 147456; int n = j / 416, k = j - n * 416;
        tw0b[j] = __float2bfloat16(k < 415 ? tw0[n * 415 + k] : 0.f);
    } else if (i < 491520) {
        int j = i - 360448; tw1b[j] = __float2bfloat16(tw1[j]);
    }
}

// ---------------- bottom layer 0: (4096,13)->(4096,512) bf16 out ----------------
__global__ __launch_bounds__(256) void bot0_kernel(
    const float* __restrict__ x, const float* __restrict__ W,
    const float* __restrict__ bias, __hip_bfloat16* __restrict__ out)
{
    int b = blockIdx.x;
    __shared__ float xr[13];
    if (threadIdx.x < 13) xr[threadIdx.x] = x[b * 13 + threadIdx.x];
    __syncthreads();
    for (int j = threadIdx.x; j < 512; j += 256) {
        const float* w = W + j * 13;
        float s = bias[j];
#pragma unroll
        for (int k = 0; k < 13; k++) s = fmaf(xr[k], w[k], s);
        out[(size_t)b * 512 + j] = __float2bfloat16(fmaxf(s, 0.f));
    }
}

// ---------------- bf16 MFMA GEMM: C = relu(A @ W^T + bias), bf16 out ----------------
// A: (M, K) bf16 row-major lda; W: (N, K) bf16 row-major ldw (K padded %32)
// tile 64x64, BK=32, 256 threads = 4 waves, each wave 32x32 (2x2 frags 16x16x32)
__global__ __launch_bounds__(256) void gemm_bf16_mfma(
    const __hip_bfloat16* __restrict__ A, int lda,
    const __hip_bfloat16* __restrict__ W, int ldw,
    const float* __restrict__ bias,
    __hip_bfloat16* __restrict__ C, int ldc,
    int ksteps)
{
    __shared__ short As[64 * 32];
    __shared__ short Bs[64 * 32];
    const int tid = threadIdx.x;
    const int lane = tid & 63;
    const int wid = tid >> 6;
    const int wr = wid >> 1, wc = wid & 1;
    const int bm = blockIdx.x * 64;
    const int bn = blockIdx.y * 64;

    // staging: thread tid loads 16B chunk -> LDS linear (row = tid>>2, chunk = tid&3)
    const int srow = tid >> 2;
    const int schunk = tid & 3;
    const short* ga = (const short*)A + (size_t)(bm + srow) * lda + schunk * 8;
    const short* gb = (const short*)W + (size_t)(bn + srow) * ldw + schunk * 8;
    short* la = As + tid * 8;
    short* lb = Bs + tid * 8;

    // fragment coords
    const int frow = lane & 15;
    const int fk   = (lane >> 4) * 8;

    f32x4 acc[2][2] = {};

    for (int ks = 0; ks < ksteps; ks++) {
        gload_lds16(ga + ks * 32, la);
        gload_lds16(gb + ks * 32, lb);
        __syncthreads();
        bf16x8 a0 = *(const bf16x8*)&As[(wr * 32 + frow) * 32 + fk];
        bf16x8 a1 = *(const bf16x8*)&As[(wr * 32 + 16 + frow) * 32 + fk];
        bf16x8 b0 = *(const bf16x8*)&Bs[(wc * 32 + frow) * 32 + fk];
        bf16x8 b1 = *(const bf16x8*)&Bs[(wc * 32 + 16 + frow) * 32 + fk];
        acc[0][0] = __builtin_amdgcn_mfma_f32_16x16x32_bf16(a0, b0, acc[0][0], 0, 0, 0);
        acc[0][1] = __builtin_amdgcn_mfma_f32_16x16x32_bf16(a0, b1, acc[0][1], 0, 0, 0);
        acc[1][0] = __builtin_amdgcn_mfma_f32_16x16x32_bf16(a1, b0, acc[1][0], 0, 0, 0);
        acc[1][1] = __builtin_amdgcn_mfma_f32_16x16x32_bf16(a1, b1, acc[1][1], 0, 0, 0);
        __syncthreads();
    }

    // epilogue: C/D layout col = lane&15, row = (lane>>4)*4 + j
    const int col0 = bn + wc * 32 + (lane & 15);
    const int row0 = bm + wr * 32 + (lane >> 4) * 4;
    float bias_n0 = bias[col0];
    float bias_n1 = bias[col0 + 16];
#pragma unroll
    for (int mi = 0; mi < 2; mi++) {
#pragma unroll
        for (int j = 0; j < 4; j++) {
            int row = row0 + mi * 16 + j;
            float v0 = fmaxf(acc[mi][0][j] + bias_n0, 0.f);
            float v1 = fmaxf(acc[mi][1][j] + bias_n1, 0.f);
            C[(size_t)row * ldc + col0]      = __float2bfloat16(v0);
            C[(size_t)row * ldc + col0 + 16] = __float2bfloat16(v1);
        }
    }
}

// ---------------- fused embedding gather + interaction -> R (bf16, 4096x416) ----------------
__global__ __launch_bounds__(256) void embed_interact_kernel(
    const int* __restrict__ idx, const float* __restrict__ emb,
    const __hip_bfloat16* __restrict__ x3, __hip_bfloat16* __restrict__ R)
{
    __shared__ float S[27 * 68];
    int b = blockIdx.x;
    int tid = threadIdx.x;
    int lane = tid & 63;
    int wid = tid >> 6;

    for (int r = wid; r < 27; r += 4) {
        float s;
        if (r == 0) {
            s = __bfloat162float(x3[(size_t)b * MM + lane]);
        } else {
            int t = r - 1;
            const int* ip = idx + ((size_t)b * TT + t) * LL;
            const float* tab = emb + (size_t)t * NROWS * MM;
            s = tab[(size_t)ip[0] * MM + lane] + tab[(size_t)ip[1] * MM + lane]
              + tab[(size_t)ip[2] * MM + lane] + tab[(size_t)ip[3] * MM + lane];
        }
        S[r * 68 + lane] = s;
    }
    __syncthreads();

    __hip_bfloat16* Rb = R + (size_t)b * RSTRIDE;
    if (tid < 64) Rb[tid] = __float2bfloat16(S[tid]);   // row 0 = x3
    if (tid == 64) Rb[415] = __float2bfloat16(0.f);     // pad col
    for (int e = tid; e < 351; e += 256) {
        int i = (int)((1.0f + sqrtf(1.0f + 8.0f * (float)e)) * 0.5f);
        while (i * (i - 1) / 2 > e) i--;
        while ((i + 1) * i / 2 <= e) i++;
        int j = e - i * (i - 1) / 2;
        const float* si = &S[i * 68];
        const float* sj = &S[j * 68];
        float s = 0.f;
#pragma unroll
        for (int k = 0; k < 16; k++) {
            float4 a = *(const float4*)&si[k * 4];
            float4 c4 = *(const float4*)&sj[k * 4];
            s += a.x * c4.x + a.y * c4.y + a.z * c4.z + a.w * c4.w;
        }
        Rb[64 + e] = __float2bfloat16(s);
    }
}

// ---------------- top layer 2: (4096,256) bf16 -> (4096,1), sigmoid ----------------
__global__ __launch_bounds__(256) void top2_kernel(
    const __hip_bfloat16* __restrict__ h, const float* __restrict__ W,
    const float* __restrict__ bias, float* __restrict__ out)
{
    __shared__ float ws[256];
    int tid = threadIdx.x;
    ws[tid] = W[tid];
    __syncthreads();
    int b = blockIdx.x * 4 + (tid >> 6);
    int lane = tid & 63;
    const unsigned short* hb = (const unsigned short*)(h + (size_t)b * 256);
    ushort4 hv = *(const ushort4*)&hb[lane * 4];
    float4 wv = *(const float4*)&ws[lane * 4];
    float s = bu2f(hv.x) * wv.x + bu2f(hv.y) * wv.y + bu2f(hv.z) * wv.z + bu2f(hv.w) * wv.w;
#pragma unroll
    for (int off = 32; off >= 1; off >>= 1)
        s += __shfl_xor(s, off, 64);
    if (lane == 0) {
        float v = s + bias[0];
        out[b] = 1.0f / (1.0f + expf(-v));
    }
}

// ---------------- launch ----------------
extern "C" void kernel_launch(void* const* d_in, const int* in_sizes, int n_in,
                              void* d_out, int out_size, void* d_ws, size_t ws_size,
                              hipStream_t stream) {
    const float* dense  = (const float*)d_in[0];
    const int*   sidx   = (const int*)d_in[1];
    const float* emb    = (const float*)d_in[2];
    const float* bw0    = (const float*)d_in[3];
    const float* bb0    = (const float*)d_in[4];
    const float* bw1    = (const float*)d_in[5];
    const float* bb1    = (const float*)d_in[6];
    const float* bw2    = (const float*)d_in[7];
    const float* bb2    = (const float*)d_in[8];
    const float* tw0    = (const float*)d_in[9];
    const float* tb0    = (const float*)d_in[10];
    const float* tw1    = (const float*)d_in[11];
    const float* tb1    = (const float*)d_in[12];
    const float* tw2    = (const float*)d_in[13];
    const float* tb2    = (const float*)d_in[14];
    float* out = (float*)d_out;

    char* wsb = (char*)d_ws;
    __hip_bfloat16* x1   = (__hip_bfloat16*)(wsb);                       // 4096x512
    __hip_bfloat16* x2   = (__hip_bfloat16*)(wsb + (4u << 20));          // 4096x256
    __hip_bfloat16* x3   = (__hip_bfloat16*)(wsb + (6u << 20));          // 4096x64
    __hip_bfloat16* R    = (__hip_bfloat16*)(wsb + (7u << 20));          // 4096x416
    __hip_bfloat16* h1   = (__hip_bfloat16*)(wsb + (11u << 20));         // 4096x512
    __hip_bfloat16* h2   = (__hip_bfloat16*)(wsb + (15u << 20));         // 4096x256
    __hip_bfloat16* bw1b = (__hip_bfloat16*)(wsb + (17u << 20));         // 256x512
    __hip_bfloat16* bw2b = bw1b + 131072;                                // 64x256
    __hip_bfloat16* tw0b = bw2b + 16384;                                 // 512x416
    __hip_bfloat16* tw1b = tw0b + 212992;                                // 256x512

    // 0. weight conversion (491520 elements)
    convert_weights<<<1920, 256, 0, stream>>>(bw1, bw2, tw0, tw1, bw1b, bw2b, tw0b, tw1b);

    // 1. bottom layer 0: dense -> x1 (4096,512)
    bot0_kernel<<<BATCH, 256, 0, stream>>>(dense, bw0, bb0, x1);

    // 2. bottom layer 1: x1 -> x2 (4096,256), K=512
    gemm_bf16_mfma<<<dim3(64, 4), 256, 0, stream>>>(x1, 512, bw1b, 512, bb1, x2, 256, 16);

    // 3. bottom layer 2: x2 -> x3 (4096,64), K=256
    gemm_bf16_mfma<<<dim3(64, 1), 256, 0, stream>>>(x2, 256, bw2b, 256, bb2, x3, 64, 8);

    // 4. fused embedding + interaction -> R (4096,416)
    embed_interact_kernel<<<BATCH, 256, 0, stream>>>(sidx, emb, x3, R);

    // 5. top layer 0: R -> h1 (4096,512), K=416
    gemm_bf16_mfma<<<dim3(64, 8), 256, 0, stream>>>(R, RSTRIDE, tw0b, 416, tb0, h1, 512, 13);

    // 6. top layer 1: h1 -> h2 (4096,256), K=512
    gemm_bf16_mfma<<<dim3(64, 4), 256, 0, stream>>>(h1, 512, tw1b, 512, tb1, h2, 256, 16);

    // 7. top layer 2: h2 -> out, sigmoid
    top2_kernel<<<BATCH / 4, 256, 0, stream>>>(h2, tw2, tb2, out);
}

// Round 3
// 55.655 us; speedup vs baseline: 3.7593x; 1.3074x over previous
//
#include <hip/hip_runtime.h>
#include <hip/hip_bf16.h>
#include <cstddef>
#include <cstdint>

// ---------------- constants ----------------
#define BATCH 4096
#define TT 26          // sparse tables
#define LL 4           // lookups per table
#define NROWS 100000
#define MM 64          // embedding dim
#define RSTR 512       // padded R row stride (64 + 351 real + 97 pad)

typedef __attribute__((ext_vector_type(8))) short bf16x8;
typedef __attribute__((ext_vector_type(4))) float f32x4;

#define AS1 __attribute__((address_space(1)))
#define AS3 __attribute__((address_space(3)))

__device__ __forceinline__ void gload_lds16(const void* g, void* l) {
    __builtin_amdgcn_global_load_lds((const AS1 unsigned int*)g,
                                     (AS3 unsigned int*)l, 16, 0, 0);
}

__device__ __forceinline__ float bu2f(unsigned short u) {
    unsigned int x = (unsigned int)u << 16;
    float f; __builtin_memcpy(&f, &x, 4); return f;
}

// ---------------- prep: weight conversion (blocks 0..2111) + bot layer 0 ----------------
// bw1b (256,512), bw2b (64,256), tw0b (512,512 zero-padded from 415), tw1b (256,512)
#define CONV_BLOCKS 2112
__global__ __launch_bounds__(256) void prep_kernel(
    const float* __restrict__ dense, const float* __restrict__ bw0,
    const float* __restrict__ bb0,
    const float* __restrict__ bw1, const float* __restrict__ bw2,
    const float* __restrict__ tw0, const float* __restrict__ tw1,
    __hip_bfloat16* __restrict__ x1,
    __hip_bfloat16* __restrict__ bw1b, __hip_bfloat16* __restrict__ bw2b,
    __hip_bfloat16* __restrict__ tw0b, __hip_bfloat16* __restrict__ tw1b)
{
    __shared__ float xr[13];
    if (blockIdx.x < CONV_BLOCKS) {
        int i = blockIdx.x * 256 + threadIdx.x;
        if (i < 131072) {
            bw1b[i] = __float2bfloat16(bw1[i]);
        } else if (i < 147456) {
            int j = i - 131072; bw2b[j] = __float2bfloat16(bw2[j]);
        } else if (i < 409600) {
            int j = i - 147456; int n = j >> 9, k = j & 511;
            tw0b[j] = __float2bfloat16(k < 415 ? tw0[n * 415 + k] : 0.f);
        } else {
            int j = i - 409600; tw1b[j] = __float2bfloat16(tw1[j]);
        }
        return;
    }
    int b = blockIdx.x - CONV_BLOCKS;
    if (threadIdx.x < 13) xr[threadIdx.x] = dense[b * 13 + threadIdx.x];
    __syncthreads();
    for (int j = threadIdx.x; j < 512; j += 256) {
        const float* w = bw0 + j * 13;
        float s = bb0[j];
#pragma unroll
        for (int k = 0; k < 13; k++) s = fmaf(xr[k], w[k], s);
        x1[(size_t)b * 512 + j] = __float2bfloat16(fmaxf(s, 0.f));
    }
}

// ---------------- full-K bf16 MFMA GEMM: C = relu(A @ W^T + bias) ----------------
// A: (M, KK) contiguous row-major; W: (N, KK) contiguous row-major.
// Tile 64x64, 4 waves (2x2 of 32x32). Entire K panel staged in LDS as two
// K-halves; counted vmcnt overlaps half-1 loads with half-0 compute.
// LDS layout: per half, [64][KK/2] shorts, byte XOR-swizzled (^ (row&7)<<4)
// via pre-swizzled global source (linear gload_lds dest) + swizzled ds_read.
template<int KK, int ACT>
__global__ __launch_bounds__(256) void gemm_fullk(
    const __hip_bfloat16* __restrict__ A,
    const __hip_bfloat16* __restrict__ W,
    const float* __restrict__ bias,
    __hip_bfloat16* __restrict__ C, int ldc)
{
    constexpr int HS   = KK / 2;            // shorts per half-row
    constexpr int CPRH = KK / 16;           // 16B chunks per half-row
    constexpr int NI   = (64 * CPRH) / 256; // gload instrs / thread / half-matrix
    __shared__ __align__(16) short As0[64 * HS];
    __shared__ __align__(16) short As1[64 * HS];
    __shared__ __align__(16) short Bs0[64 * HS];
    __shared__ __align__(16) short Bs1[64 * HS];

    const int tid  = threadIdx.x;
    const int lane = tid & 63;
    const int wid  = tid >> 6;
    const int wr   = wid >> 1, wc = wid & 1;

    const char* Ab = (const char*)A + (size_t)blockIdx.x * (64 * KK * 2);
    const char* Wb = (const char*)W + (size_t)blockIdx.y * (64 * KK * 2);

    auto stage = [&](const char* Gb, short* Ls, int h) {
#pragma unroll
        for (int j = 0; j < NI; j++) {
            int ci  = j * 256 + tid;
            int row = ci / CPRH;                       // power-of-2 divide
            int cb  = (ci & (CPRH - 1)) * 16;          // bytes within half-row
            int src = row * (2 * KK) + h * KK + (cb ^ ((row & 7) << 4));
            gload_lds16(Gb + src, (char*)Ls + row * KK + cb);
        }
    };
    stage(Ab, As0, 0); stage(Wb, Bs0, 0);
    stage(Ab, As1, 1); stage(Wb, Bs1, 1);

    const int frow = lane & 15;
    const int fkb  = (lane >> 4) * 16;     // frag k sub-offset (bytes)
    const int xr   = (frow & 7) << 4;      // read-side swizzle
    const int oA0  = (wr * 32 + frow) * KK;          // byte row bases (row*KK bytes)
    const int oA1  = oA0 + 16 * KK;
    const int oB0  = (wc * 32 + frow) * KK;
    const int oB1  = oB0 + 16 * KK;

    f32x4 acc[2][2] = {};

    auto compute = [&](const short* Ah, const short* Bh) {
#pragma unroll
        for (int ks = 0; ks < KK / 64; ks++) {
            int pc = (ks * 64 + fkb) ^ xr;
            bf16x8 a0 = *(const bf16x8*)((const char*)Ah + oA0 + pc);
            bf16x8 a1 = *(const bf16x8*)((const char*)Ah + oA1 + pc);
            bf16x8 b0 = *(const bf16x8*)((const char*)Bh + oB0 + pc);
            bf16x8 b1 = *(const bf16x8*)((const char*)Bh + oB1 + pc);
            acc[0][0] = __builtin_amdgcn_mfma_f32_16x16x32_bf16(a0, b0, acc[0][0], 0, 0, 0);
            acc[0][1] = __builtin_amdgcn_mfma_f32_16x16x32_bf16(a0, b1, acc[0][1], 0, 0, 0);
            acc[1][0] = __builtin_amdgcn_mfma_f32_16x16x32_bf16(a1, b0, acc[1][0], 0, 0, 0);
            acc[1][1] = __builtin_amdgcn_mfma_f32_16x16x32_bf16(a1, b1, acc[1][1], 0, 0, 0);
        }
    };

    // wait half-0 only (per-wave FIFO: first 2*NI loads are half-0), barrier
    asm volatile("s_waitcnt vmcnt(%0)" :: "i"(2 * NI) : "memory");
    __builtin_amdgcn_sched_barrier(0);
    __builtin_amdgcn_s_barrier();
    __builtin_amdgcn_sched_barrier(0);
    compute(As0, Bs0);
    asm volatile("s_waitcnt vmcnt(0)" ::: "memory");
    __builtin_amdgcn_sched_barrier(0);
    __builtin_amdgcn_s_barrier();
    __builtin_amdgcn_sched_barrier(0);
    compute(As1, Bs1);

    // epilogue: C/D map col = lane&15, row = (lane>>4)*4 + j
    const int col0 = blockIdx.y * 64 + wc * 32 + (lane & 15);
    const int row0 = blockIdx.x * 64 + wr * 32 + (lane >> 4) * 4;
    float bias_n0 = bias[col0];
    float bias_n1 = bias[col0 + 16];
#pragma unroll
    for (int mi = 0; mi < 2; mi++) {
#pragma unroll
        for (int j = 0; j < 4; j++) {
            int row = row0 + mi * 16 + j;
            float v0 = acc[mi][0][j] + bias_n0;
            float v1 = acc[mi][1][j] + bias_n1;
            if (ACT == 1) { v0 = fmaxf(v0, 0.f); v1 = fmaxf(v1, 0.f); }
            C[(size_t)row * ldc + col0]      = __float2bfloat16(v0);
            C[(size_t)row * ldc + col0 + 16] = __float2bfloat16(v1);
        }
    }
}

// ---------------- fused embedding gather + interaction -> R ----------------
// R row: [0..63] = x3 (already written by bot2 GEMM), [64..414] = Zflat, [415..511] = 0
__global__ __launch_bounds__(256) void embed_interact_kernel(
    const int* __restrict__ idx, const float* __restrict__ emb,
    __hip_bfloat16* __restrict__ R)
{
    __shared__ float S[27 * 68];
    __shared__ int sidx[TT * LL];
    const int b = blockIdx.x;
    const int tid = threadIdx.x;
    const int lane = tid & 63;
    const int wid = tid >> 6;

    if (tid < TT * LL) sidx[tid] = idx[(size_t)b * (TT * LL) + tid];
    __syncthreads();

    // phase 1: issue all row loads into registers (max MLP), then sum
    float v[7][4];
#pragma unroll
    for (int rr = 0; rr < 7; rr++) {
        const int r = rr * 4 + wid;
        if (r == 0) {
            v[rr][0] = __bfloat162float(R[(size_t)b * RSTR + lane]);
            v[rr][1] = 0.f; v[rr][2] = 0.f; v[rr][3] = 0.f;
        } else if (r < 27) {
            const int t = r - 1;
            const float* tab = emb + (size_t)t * NROWS * MM;
#pragma unroll
            for (int l = 0; l < LL; l++)
                v[rr][l] = tab[(size_t)sidx[t * LL + l] * MM + lane];
        }
    }
#pragma unroll
    for (int rr = 0; rr < 7; rr++) {
        const int r = rr * 4 + wid;
        if (r < 27) S[r * 68 + lane] = v[rr][0] + v[rr][1] + v[rr][2] + v[rr][3];
    }
    __syncthreads();

    __hip_bfloat16* Rb = R + (size_t)b * RSTR;
    if (tid < 97) Rb[415 + tid] = __float2bfloat16(0.f);   // K pad
    for (int e = tid; e < 351; e += 256) {
        int i = (int)((1.0f + sqrtf(1.0f + 8.0f * (float)e)) * 0.5f);
        while (i * (i - 1) / 2 > e) i--;
        while ((i + 1) * i / 2 <= e) i++;
        int j = e - i * (i - 1) / 2;
        const float* si_ = &S[i * 68];
        const float* sj_ = &S[j * 68];
        float s = 0.f;
#pragma unroll
        for (int k = 0; k < 16; k++) {
            float4 a  = *(const float4*)&si_[k * 4];
            float4 c4 = *(const float4*)&sj_[k * 4];
            s += a.x * c4.x + a.y * c4.y + a.z * c4.z + a.w * c4.w;
        }
        Rb[64 + e] = __float2bfloat16(s);
    }
}

// ---------------- top layer 2: (4096,256) bf16 -> (4096,1), sigmoid ----------------
__global__ __launch_bounds__(256) void top2_kernel(
    const __hip_bfloat16* __restrict__ h, const float* __restrict__ W,
    const float* __restrict__ bias, float* __restrict__ out)
{
    __shared__ float ws[256];
    int tid = threadIdx.x;
    ws[tid] = W[tid];
    __syncthreads();
    int b = blockIdx.x * 4 + (tid >> 6);
    int lane = tid & 63;
    const unsigned short* hb = (const unsigned short*)(h + (size_t)b * 256);
    ushort4 hv = *(const ushort4*)&hb[lane * 4];
    float4 wv = *(const float4*)&ws[lane * 4];
    float s = bu2f(hv.x) * wv.x + bu2f(hv.y) * wv.y + bu2f(hv.z) * wv.z + bu2f(hv.w) * wv.w;
#pragma unroll
    for (int off = 32; off >= 1; off >>= 1)
        s += __shfl_xor(s, off, 64);
    if (lane == 0) {
        float v = s + bias[0];
        out[b] = 1.0f / (1.0f + expf(-v));
    }
}

// ---------------- launch ----------------
extern "C" void kernel_launch(void* const* d_in, const int* in_sizes, int n_in,
                              void* d_out, int out_size, void* d_ws, size_t ws_size,
                              hipStream_t stream) {
    const float* dense = (const float*)d_in[0];
    const int*   sidx  = (const int*)d_in[1];
    const float* emb   = (const float*)d_in[2];
    const float* bw0   = (const float*)d_in[3];
    const float* bb0   = (const float*)d_in[4];
    const float* bw1   = (const float*)d_in[5];
    const float* bb1   = (const float*)d_in[6];
    const float* bw2   = (const float*)d_in[7];
    const float* bb2   = (const float*)d_in[8];
    const float* tw0   = (const float*)d_in[9];
    const float* tb0   = (const float*)d_in[10];
    const float* tw1   = (const float*)d_in[11];
    const float* tb1   = (const float*)d_in[12];
    const float* tw2   = (const float*)d_in[13];
    const float* tb2   = (const float*)d_in[14];
    float* out = (float*)d_out;

    char* wsb = (char*)d_ws;
    __hip_bfloat16* x1   = (__hip_bfloat16*)(wsb);                 // 4096x512
    __hip_bfloat16* x2   = (__hip_bfloat16*)(wsb + (4u << 20));    // 4096x256
    __hip_bfloat16* R    = (__hip_bfloat16*)(wsb + (8u << 20));    // 4096x512
    __hip_bfloat16* h1   = (__hip_bfloat16*)(wsb + (12u << 20));   // 4096x512
    __hip_bfloat16* h2   = (__hip_bfloat16*)(wsb + (16u << 20));   // 4096x256
    __hip_bfloat16* bw1b = (__hip_bfloat16*)(wsb + (18u << 20));   // 256x512
    __hip_bfloat16* bw2b = bw1b + 131072;                          // 64x256
    __hip_bfloat16* tw0b = bw2b + 16384;                           // 512x512
    __hip_bfloat16* tw1b = tw0b + 262144;                          // 256x512

    // 1. weight conversion + bottom layer 0
    prep_kernel<<<CONV_BLOCKS + BATCH, 256, 0, stream>>>(
        dense, bw0, bb0, bw1, bw2, tw0, tw1, x1, bw1b, bw2b, tw0b, tw1b);

    // 2. bottom layer 1: x1 (4096,512) -> x2 (4096,256)
    gemm_fullk<512, 1><<<dim3(64, 4), 256, 0, stream>>>(x1, bw1b, bb1, x2, 256);

    // 3. bottom layer 2: x2 (4096,256) -> R[:, 0:64] (x3 in place)
    gemm_fullk<256, 1><<<dim3(64, 1), 256, 0, stream>>>(x2, bw2b, bb2, R, RSTR);

    // 4. fused embedding + interaction -> R[:, 64:512]
    embed_interact_kernel<<<BATCH, 256, 0, stream>>>(sidx, emb, R);

    // 5. top layer 0: R (4096,512) -> h1 (4096,512)
    gemm_fullk<512, 1><<<dim3(64, 8), 256, 0, stream>>>(R, tw0b, tb0, h1, 512);

    // 6. top layer 1: h1 (4096,512) -> h2 (4096,256)
    gemm_fullk<512, 1><<<dim3(64, 4), 256, 0, stream>>>(h1, tw1b, tb1, h2, 256);

    // 7. top layer 2: h2 -> out, sigmoid
    top2_kernel<<<BATCH / 4, 256, 0, stream>>>(h2, tw2, tb2, out);
}